// Round 1
// baseline (829.476 us; speedup 1.0000x reference)
//
#include <hip/hip_runtime.h>
#include <math.h>

// Problem constants
#define NB 128
#define HD 1024
#define FHH 24
#define FWW 48

// ws layout (float offsets). tpart region (4 MB) is reused as psum for the
// final GEMM (both 1,048,576 floats) since tpart is dead after k_align.
#define OFF_TPART 0u          // 4*128*2048 = 1048576  (later: psum 8*128*1024)
#define OFF_X0    1048576u    // 128
#define OFF_Y0    1048704u    // 128
#define OFF_WXN   1048832u    // 128*48
#define OFF_WYN   1054976u    // 128*24
#define OFF_ATTN  1058048u    // 2*128*1024 (two row-parity partials)

// ---------------------------------------------------------------------------
// K1a: tpart[ks][b][j] = sum_{k in ks-chunk} hid[b,k] * W1[j,k]
// grid (64 j-tiles of 32, 4 k-chunks of 256), 256 threads
// ---------------------------------------------------------------------------
__global__ __launch_bounds__(256) void k_gemm1(
    const float* __restrict__ hid, const float* __restrict__ W1,
    float* __restrict__ tpart) {
  __shared__ float xs[128][36];   // [b][kk], stride 36 keeps 16B alignment
  __shared__ float wsh[32][36];   // [j_local][kk]
  const int tid = threadIdx.x;
  const int jt = blockIdx.x;
  const int ks = blockIdx.y;
  const int ty = tid >> 3, tx = tid & 7;
  const int b0 = ty * 4, jl = tx * 4;
  float acc[4][4] = {{0.f, 0.f, 0.f, 0.f}};
  for (int kt = 0; kt < 8; ++kt) {
    const int k0 = ks * 256 + kt * 32;
#pragma unroll
    for (int i = 0; i < 4; ++i) {
      int idx = tid + 256 * i;            // 0..1023
      int bb = idx >> 3, q = idx & 7;
      float4 g = *(const float4*)(hid + bb * 1024 + k0 + q * 4);
      *(float4*)&xs[bb][q * 4] = g;
    }
    {
      int o = tid >> 3, q = tid & 7;      // 32 rows x 8 quads
      float4 g = *(const float4*)(W1 + (size_t)(jt * 32 + o) * 1024 + k0 + q * 4);
      *(float4*)&wsh[o][q * 4] = g;
    }
    __syncthreads();
#pragma unroll
    for (int kk = 0; kk < 32; ++kk) {
      float xa[4], wb[4];
#pragma unroll
      for (int u = 0; u < 4; ++u) xa[u] = xs[b0 + u][kk];
#pragma unroll
      for (int v = 0; v < 4; ++v) wb[v] = wsh[jl + v][kk];
#pragma unroll
      for (int u = 0; u < 4; ++u)
#pragma unroll
        for (int v = 0; v < 4; ++v)
          acc[u][v] = fmaf(xa[u], wb[v], acc[u][v]);
    }
    __syncthreads();
  }
#pragma unroll
  for (int u = 0; u < 4; ++u)
#pragma unroll
    for (int v = 0; v < 4; ++v)
      tpart[(size_t)ks * (128u * 2048u) + (size_t)(b0 + u) * 2048u +
            (jt * 32 + jl + v)] = acc[u][v];
}

// ---------------------------------------------------------------------------
// K1b: per-b: t = tanh(sum_ks tpart + b1); algn = sigmoid(t@W2.T + b2);
// x0 = algn0*48, y0 = algn1*24; normalized separable Gaussian weights.
// grid 128 (one block per b), 256 threads
// ---------------------------------------------------------------------------
__global__ __launch_bounds__(256) void k_align(
    const float* __restrict__ tpart, const float* __restrict__ b1,
    const float* __restrict__ W2, const float* __restrict__ b2,
    float* __restrict__ x0a, float* __restrict__ y0a,
    float* __restrict__ wxn, float* __restrict__ wyn) {
  const int b = blockIdx.x;
  const int tid = threadIdx.x;
  float a0 = 0.f, a1 = 0.f;
#pragma unroll
  for (int i = 0; i < 8; ++i) {
    int j = tid + 256 * i;
    float s = b1[j];
    s += tpart[0u * 262144u + (size_t)b * 2048u + j];
    s += tpart[1u * 262144u + (size_t)b * 2048u + j];
    s += tpart[2u * 262144u + (size_t)b * 2048u + j];
    s += tpart[3u * 262144u + (size_t)b * 2048u + j];
    float tv = tanhf(s);
    a0 += tv * W2[j];
    a1 += tv * W2[2048 + j];
  }
  __shared__ float r0[256], r1[256];
  r0[tid] = a0; r1[tid] = a1;
  __syncthreads();
  for (int s = 128; s > 0; s >>= 1) {
    if (tid < s) { r0[tid] += r0[tid + s]; r1[tid] += r1[tid + s]; }
    __syncthreads();
  }
  __shared__ float xy[2];
  __shared__ float wxl[48], wyl[24];
  __shared__ float invZ[2];
  if (tid == 0) {
    float p0 = 1.f / (1.f + expf(-(r0[0] + b2[0])));
    float p1 = 1.f / (1.f + expf(-(r1[0] + b2[1])));
    xy[0] = p0 * 48.f;
    xy[1] = p1 * 24.f;
  }
  __syncthreads();
  float x0 = xy[0], y0 = xy[1];
  if (tid < 48) {
    float d = (float)tid - x0;
    wxl[tid] = expf(-d * d * (1.f / 32.f));
  } else if (tid >= 64 && tid < 88) {
    int r = tid - 64;
    float d = (float)r - y0;
    wyl[r] = expf(-d * d * (1.f / 32.f));
  }
  __syncthreads();
  if (tid == 0) {
    float zx = 0.f, zy = 0.f;
    for (int c = 0; c < 48; ++c) zx += wxl[c];
    for (int r = 0; r < 24; ++r) zy += wyl[r];
    invZ[0] = 1.f / zx;
    invZ[1] = 1.f / zy;
  }
  __syncthreads();
  if (tid < 48) wxn[b * 48 + tid] = wxl[tid] * invZ[0];
  else if (tid >= 64 && tid < 88) wyn[b * 24 + (tid - 64)] = wyl[tid - 64] * invZ[1];
  if (tid == 0) { x0a[b] = x0; y0a[b] = y0; }
}

// ---------------------------------------------------------------------------
// K2: attn_part[z][b][h] = sum over truncated Gaussian window (radius 12 = 3
// sigma, per-row circular c-range) of w[r,c] * V[r,c,b,h], rows r%2-split
// across z. grid (128 b, 2 h-halves, 2 parities), 256 threads, float2/lane.
// ---------------------------------------------------------------------------
__global__ __launch_bounds__(256) void k_attn(
    const float* __restrict__ V, const float* __restrict__ x0a,
    const float* __restrict__ y0a, const float* __restrict__ wxn,
    const float* __restrict__ wyn, float* __restrict__ attnp) {
  const int b = blockIdx.x;
  const int half = blockIdx.y;
  const int z = blockIdx.z;
  const int tid = threadIdx.x;
  __shared__ float wxl[48], wyl[24];
  __shared__ float xy[2];
  if (tid < 48) wxl[tid] = wxn[b * 48 + tid];
  else if (tid >= 64 && tid < 88) wyl[tid - 64] = wyn[b * 24 + (tid - 64)];
  if (tid == 96) xy[0] = x0a[b];
  if (tid == 97) xy[1] = y0a[b];
  __syncthreads();
  const float x0 = xy[0], y0 = xy[1];
  const int h0 = half * 512 + tid * 2;
  float accx = 0.f, accy = 0.f;
  const int r0 = max(0, (int)ceilf(y0 - 12.f));
  const int r1 = min(23, (int)floorf(y0 + 12.f));
  for (int r = r0 + z; r <= r1; r += 2) {
    float dy = (float)r - y0;
    float rem = 144.f - dy * dy;
    float rad = sqrtf(fmaxf(rem, 0.f));
    int c0 = max(0, (int)ceilf(x0 - rad));
    int c1 = min(47, (int)floorf(x0 + rad));
    float wy = wyl[r];
    for (int c = c0; c <= c1; ++c) {
      float w = wy * wxl[c];
      const float2 v =
          *(const float2*)(V + ((size_t)((r * 48 + c) * 128 + b)) * 1024u + h0);
      accx += w * v.x;
      accy += w * v.y;
    }
  }
  float2 o; o.x = accx; o.y = accy;
  *(float2*)(attnp + (size_t)z * 131072u + (size_t)b * 1024u + h0) = o;
}

// ---------------------------------------------------------------------------
// K3: psum[ks][b][o] = sum_{k in ks-chunk} x[b,k] * Wc[o,k],
// x = concat(inp, attn_part0 + attn_part1). grid (32 o-tiles, 8 k-chunks).
// ---------------------------------------------------------------------------
__global__ __launch_bounds__(256) void k_gemm2(
    const float* __restrict__ inp, const float* __restrict__ attnp,
    const float* __restrict__ Wc, float* __restrict__ psum) {
  __shared__ float xs[128][36];
  __shared__ float wsh[32][36];
  const int tid = threadIdx.x;
  const int ot = blockIdx.x;
  const int ks = blockIdx.y;
  const int ty = tid >> 3, tx = tid & 7;
  const int b0 = ty * 4, ol = tx * 4;
  float acc[4][4] = {{0.f, 0.f, 0.f, 0.f}};
  for (int kt = 0; kt < 8; ++kt) {
    const int k0 = ks * 256 + kt * 32;
#pragma unroll
    for (int i = 0; i < 4; ++i) {
      int idx = tid + 256 * i;
      int bb = idx >> 3, q = idx & 7;
      float4 g;
      if (ks < 4) {
        g = *(const float4*)(inp + bb * 1024 + k0 + q * 4);
      } else {
        const float* p = attnp + bb * 1024 + (k0 - 1024) + q * 4;
        float4 ga = *(const float4*)p;
        float4 gb = *(const float4*)(p + 131072);
        g.x = ga.x + gb.x; g.y = ga.y + gb.y;
        g.z = ga.z + gb.z; g.w = ga.w + gb.w;
      }
      *(float4*)&xs[bb][q * 4] = g;
    }
    {
      int o = tid >> 3, q = tid & 7;
      float4 g = *(const float4*)(Wc + (size_t)(ot * 32 + o) * 2048u + k0 + q * 4);
      *(float4*)&wsh[o][q * 4] = g;
    }
    __syncthreads();
#pragma unroll
    for (int kk = 0; kk < 32; ++kk) {
      float xa[4], wb[4];
#pragma unroll
      for (int u = 0; u < 4; ++u) xa[u] = xs[b0 + u][kk];
#pragma unroll
      for (int v = 0; v < 4; ++v) wb[v] = wsh[ol + v][kk];
#pragma unroll
      for (int u = 0; u < 4; ++u)
#pragma unroll
        for (int v = 0; v < 4; ++v)
          acc[u][v] = fmaf(xa[u], wb[v], acc[u][v]);
    }
    __syncthreads();
  }
#pragma unroll
  for (int u = 0; u < 4; ++u)
#pragma unroll
    for (int v = 0; v < 4; ++v)
      psum[(size_t)ks * 131072u + (size_t)(b0 + u) * 1024u +
           (ot * 32 + ol + v)] = acc[u][v];
}

// ---------------------------------------------------------------------------
// K4: out[b][o] = relu(sum_ks psum + bc[o])
// ---------------------------------------------------------------------------
__global__ __launch_bounds__(256) void k_final(
    const float* __restrict__ psum, const float* __restrict__ bc,
    float* __restrict__ out) {
  const int gid = blockIdx.x * 256 + threadIdx.x;  // 0..131071
  const int o = gid & 1023;
  float s = bc[o];
#pragma unroll
  for (int i = 0; i < 8; ++i) s += psum[(size_t)i * 131072u + gid];
  out[gid] = fmaxf(s, 0.f);
}

extern "C" void kernel_launch(void* const* d_in, const int* in_sizes, int n_in,
                              void* d_out, int out_size, void* d_ws,
                              size_t ws_size, hipStream_t stream) {
  const float* inp = (const float*)d_in[0];
  const float* hid = (const float*)d_in[1];
  const float* V   = (const float*)d_in[2];
  const float* W1  = (const float*)d_in[3];
  const float* b1  = (const float*)d_in[4];
  const float* W2  = (const float*)d_in[5];
  const float* b2  = (const float*)d_in[6];
  const float* Wc  = (const float*)d_in[7];
  const float* bc  = (const float*)d_in[8];
  float* out = (float*)d_out;
  float* ws = (float*)d_ws;

  float* tpart = ws + OFF_TPART;   // also psum for k_gemm2/k_final
  float* x0a   = ws + OFF_X0;
  float* y0a   = ws + OFF_Y0;
  float* wxn   = ws + OFF_WXN;
  float* wyn   = ws + OFF_WYN;
  float* attnp = ws + OFF_ATTN;

  k_gemm1<<<dim3(64, 4), 256, 0, stream>>>(hid, W1, tpart);
  k_align<<<128, 256, 0, stream>>>(tpart, b1, W2, b2, x0a, y0a, wxn, wyn);
  k_attn<<<dim3(128, 2, 2), 256, 0, stream>>>(V, x0a, y0a, wxn, wyn, attnp);
  k_gemm2<<<dim3(32, 8), 256, 0, stream>>>(inp, attnp, Wc, tpart);
  k_final<<<512, 256, 0, stream>>>(tpart, bc, out);
}

// Round 2
// 743.053 us; speedup vs baseline: 1.1163x; 1.1163x over previous
//
#include <hip/hip_runtime.h>
#include <math.h>

// Problem constants
#define NB 128
#define HD 1024
#define FHH 24
#define FWW 48

// ws layout (float offsets). tpart region (8 MB) is reused as psum for the
// final GEMM (8*128*1024 floats fit inside 8*128*2048) since tpart is dead
// after k_align.
#define OFF_TPART 0u          // 8*128*2048 = 2097152
#define OFF_X0    2097152u    // 128
#define OFF_Y0    2097280u    // 128
#define OFF_WXN   2097408u    // 128*48 = 6144
#define OFF_WYN   2103552u    // 128*24 = 3072
#define OFF_ATTN  2106624u    // 128*1024 = 131072 (no partials)

// ---------------------------------------------------------------------------
// K1a: tpart[ks][b][j] = sum_{k in ks-chunk(128)} hid[b,k] * W1[j,k]
// grid (64 j-tiles of 32, 8 k-chunks of 128), 256 threads.
// LDS transposed to [kk][b] / [kk][j] so fragment reads are ds_read_b128.
// ---------------------------------------------------------------------------
__global__ __launch_bounds__(256) void k_gemm1(
    const float* __restrict__ hid, const float* __restrict__ W1,
    float* __restrict__ tpart) {
  __shared__ float xs[32][132];   // [kk][b], pad 132
  __shared__ float wsh[32][36];   // [kk][j_local], pad 36
  const int tid = threadIdx.x;
  const int jt = blockIdx.x;
  const int ks = blockIdx.y;
  const int ty = tid >> 3, tx = tid & 7;
  const int b0 = ty * 4, jl = tx * 4;
  float acc[4][4] = {{0.f, 0.f, 0.f, 0.f}};
  for (int kt = 0; kt < 4; ++kt) {
    const int k0 = ks * 128 + kt * 32;
#pragma unroll
    for (int i = 0; i < 4; ++i) {
      int idx = tid + 256 * i;            // 0..1023 = 128 b x 8 q
      int bb = idx >> 3, q = idx & 7;
      float4 g = *(const float4*)(hid + bb * 1024 + k0 + q * 4);
      xs[q * 4 + 0][bb] = g.x;
      xs[q * 4 + 1][bb] = g.y;
      xs[q * 4 + 2][bb] = g.z;
      xs[q * 4 + 3][bb] = g.w;
    }
    {
      int o = tid >> 3, q = tid & 7;      // 32 rows x 8 quads
      float4 g = *(const float4*)(W1 + (size_t)(jt * 32 + o) * 1024 + k0 + q * 4);
      wsh[q * 4 + 0][o] = g.x;
      wsh[q * 4 + 1][o] = g.y;
      wsh[q * 4 + 2][o] = g.z;
      wsh[q * 4 + 3][o] = g.w;
    }
    __syncthreads();
#pragma unroll
    for (int kk = 0; kk < 32; ++kk) {
      float4 xa = *(const float4*)&xs[kk][b0];
      float4 wb = *(const float4*)&wsh[kk][jl];
      acc[0][0] = fmaf(xa.x, wb.x, acc[0][0]);
      acc[0][1] = fmaf(xa.x, wb.y, acc[0][1]);
      acc[0][2] = fmaf(xa.x, wb.z, acc[0][2]);
      acc[0][3] = fmaf(xa.x, wb.w, acc[0][3]);
      acc[1][0] = fmaf(xa.y, wb.x, acc[1][0]);
      acc[1][1] = fmaf(xa.y, wb.y, acc[1][1]);
      acc[1][2] = fmaf(xa.y, wb.z, acc[1][2]);
      acc[1][3] = fmaf(xa.y, wb.w, acc[1][3]);
      acc[2][0] = fmaf(xa.z, wb.x, acc[2][0]);
      acc[2][1] = fmaf(xa.z, wb.y, acc[2][1]);
      acc[2][2] = fmaf(xa.z, wb.z, acc[2][2]);
      acc[2][3] = fmaf(xa.z, wb.w, acc[2][3]);
      acc[3][0] = fmaf(xa.w, wb.x, acc[3][0]);
      acc[3][1] = fmaf(xa.w, wb.y, acc[3][1]);
      acc[3][2] = fmaf(xa.w, wb.z, acc[3][2]);
      acc[3][3] = fmaf(xa.w, wb.w, acc[3][3]);
    }
    __syncthreads();
  }
#pragma unroll
  for (int u = 0; u < 4; ++u) {
    float4 o;
    o.x = acc[u][0]; o.y = acc[u][1]; o.z = acc[u][2]; o.w = acc[u][3];
    *(float4*)(tpart + (size_t)ks * 262144u + (size_t)(b0 + u) * 2048u +
               (jt * 32 + jl)) = o;
  }
}

// ---------------------------------------------------------------------------
// K1b: per-b: t = tanh(sum_ks tpart + b1); algn = sigmoid(t@W2.T + b2);
// x0 = algn0*48, y0 = algn1*24; normalized separable Gaussian weights
// (normalization over the FULL grid, exact).
// grid 128 (one block per b), 256 threads
// ---------------------------------------------------------------------------
__global__ __launch_bounds__(256) void k_align(
    const float* __restrict__ tpart, const float* __restrict__ b1,
    const float* __restrict__ W2, const float* __restrict__ b2,
    float* __restrict__ x0a, float* __restrict__ y0a,
    float* __restrict__ wxn, float* __restrict__ wyn) {
  const int b = blockIdx.x;
  const int tid = threadIdx.x;
  float a0 = 0.f, a1 = 0.f;
#pragma unroll
  for (int i = 0; i < 8; ++i) {
    int j = tid + 256 * i;
    float s = b1[j];
#pragma unroll
    for (int ks = 0; ks < 8; ++ks)
      s += tpart[(size_t)ks * 262144u + (size_t)b * 2048u + j];
    float tv = tanhf(s);
    a0 += tv * W2[j];
    a1 += tv * W2[2048 + j];
  }
  __shared__ float r0[256], r1[256];
  r0[tid] = a0; r1[tid] = a1;
  __syncthreads();
  for (int s = 128; s > 0; s >>= 1) {
    if (tid < s) { r0[tid] += r0[tid + s]; r1[tid] += r1[tid + s]; }
    __syncthreads();
  }
  __shared__ float xy[2];
  __shared__ float wxl[48], wyl[24];
  __shared__ float invZ[2];
  if (tid == 0) {
    float p0 = 1.f / (1.f + expf(-(r0[0] + b2[0])));
    float p1 = 1.f / (1.f + expf(-(r1[0] + b2[1])));
    xy[0] = p0 * 48.f;
    xy[1] = p1 * 24.f;
  }
  __syncthreads();
  float x0 = xy[0], y0 = xy[1];
  if (tid < 48) {
    float d = (float)tid - x0;
    wxl[tid] = expf(-d * d * (1.f / 32.f));
  } else if (tid >= 64 && tid < 88) {
    int r = tid - 64;
    float d = (float)r - y0;
    wyl[r] = expf(-d * d * (1.f / 32.f));
  }
  __syncthreads();
  if (tid == 0) {
    float zx = 0.f, zy = 0.f;
    for (int c = 0; c < 48; ++c) zx += wxl[c];
    for (int r = 0; r < 24; ++r) zy += wyl[r];
    invZ[0] = 1.f / zx;
    invZ[1] = 1.f / zy;
  }
  __syncthreads();
  if (tid < 48) wxn[b * 48 + tid] = wxl[tid] * invZ[0];
  else if (tid >= 64 && tid < 88) wyn[b * 24 + (tid - 64)] = wyl[tid - 64] * invZ[1];
  if (tid == 0) { x0a[b] = x0; y0a[b] = y0; }
}

// ---------------------------------------------------------------------------
// K2: attn[b][h] over truncated Gaussian window (radius 12 = 3 sigma,
// per-row circular c-range). grid (128 b, 4 h-quarters), 512 threads =
// 8 waves; wave w owns rows r ≡ w (mod 8); float4/lane (1 KB/wave contiguous);
// cross-wave LDS reduce at the end -> attn written directly, no partials.
// ---------------------------------------------------------------------------
__global__ __launch_bounds__(512) void k_attn(
    const float* __restrict__ V, const float* __restrict__ x0a,
    const float* __restrict__ y0a, const float* __restrict__ wxn,
    const float* __restrict__ wyn, float* __restrict__ attn) {
  const int b = blockIdx.x;
  const int qtr = blockIdx.y;
  const int tid = threadIdx.x;
  const int w = tid >> 6;
  const int lane = tid & 63;
  __shared__ float wxl[48], wyl[24];
  __shared__ float xy[2];
  __shared__ float red[8][260];
  if (tid < 48) wxl[tid] = wxn[b * 48 + tid];
  else if (tid >= 64 && tid < 88) wyl[tid - 64] = wyn[b * 24 + (tid - 64)];
  if (tid == 96) xy[0] = x0a[b];
  if (tid == 97) xy[1] = y0a[b];
  __syncthreads();
  const float x0 = xy[0], y0 = xy[1];
  const int h0 = qtr * 256 + lane * 4;
  float4 acc; acc.x = 0.f; acc.y = 0.f; acc.z = 0.f; acc.w = 0.f;
  const int rlo = max(0, (int)ceilf(y0 - 12.f));
  const int rhi = min(23, (int)floorf(y0 + 12.f));
  for (int r = w; r < 24; r += 8) {
    if (r < rlo || r > rhi) continue;
    float dy = (float)r - y0;
    float rad = sqrtf(fmaxf(144.f - dy * dy, 0.f));
    int c0 = max(0, (int)ceilf(x0 - rad));
    int c1 = min(47, (int)floorf(x0 + rad));
    float wy = wyl[r];
    const float* base = V + ((size_t)((r * 48 + c0) * 128 + b)) * 1024u + h0;
#pragma unroll 4
    for (int c = c0; c <= c1; ++c) {
      float wgt = wy * wxl[c];
      const float4 v = *(const float4*)(base + (size_t)(c - c0) * 131072u);
      acc.x = fmaf(wgt, v.x, acc.x);
      acc.y = fmaf(wgt, v.y, acc.y);
      acc.z = fmaf(wgt, v.z, acc.z);
      acc.w = fmaf(wgt, v.w, acc.w);
    }
  }
  *(float4*)&red[w][lane * 4] = acc;
  __syncthreads();
  if (tid < 256) {
    float s = 0.f;
#pragma unroll
    for (int ww = 0; ww < 8; ++ww) s += red[ww][tid];
    attn[(size_t)b * 1024u + qtr * 256 + tid] = s;
  }
}

// ---------------------------------------------------------------------------
// K3: psum[ks][b][o] = sum_{k in ks-chunk(256)} x[b,k] * Wc[o,k],
// x = concat(inp, attn). grid (32 o-tiles, 8 k-chunks), 256 threads.
// ---------------------------------------------------------------------------
__global__ __launch_bounds__(256) void k_gemm2(
    const float* __restrict__ inp, const float* __restrict__ attn,
    const float* __restrict__ Wc, float* __restrict__ psum) {
  __shared__ float xs[32][132];
  __shared__ float wsh[32][36];
  const int tid = threadIdx.x;
  const int ot = blockIdx.x;
  const int ks = blockIdx.y;
  const int ty = tid >> 3, tx = tid & 7;
  const int b0 = ty * 4, ol = tx * 4;
  const float* xsrc = (ks < 4) ? inp : attn;
  const int kbase = (ks < 4) ? ks * 256 : (ks - 4) * 256;
  float acc[4][4] = {{0.f, 0.f, 0.f, 0.f}};
  for (int kt = 0; kt < 8; ++kt) {
    const int k0g = ks * 256 + kt * 32;      // index into Wc's K dim
    const int k0x = kbase + kt * 32;         // index into xsrc
#pragma unroll
    for (int i = 0; i < 4; ++i) {
      int idx = tid + 256 * i;
      int bb = idx >> 3, q = idx & 7;
      float4 g = *(const float4*)(xsrc + bb * 1024 + k0x + q * 4);
      xs[q * 4 + 0][bb] = g.x;
      xs[q * 4 + 1][bb] = g.y;
      xs[q * 4 + 2][bb] = g.z;
      xs[q * 4 + 3][bb] = g.w;
    }
    {
      int o = tid >> 3, q = tid & 7;
      float4 g = *(const float4*)(Wc + (size_t)(ot * 32 + o) * 2048u + k0g + q * 4);
      wsh[q * 4 + 0][o] = g.x;
      wsh[q * 4 + 1][o] = g.y;
      wsh[q * 4 + 2][o] = g.z;
      wsh[q * 4 + 3][o] = g.w;
    }
    __syncthreads();
#pragma unroll
    for (int kk = 0; kk < 32; ++kk) {
      float4 xa = *(const float4*)&xs[kk][b0];
      float4 wb = *(const float4*)&wsh[kk][ol];
      acc[0][0] = fmaf(xa.x, wb.x, acc[0][0]);
      acc[0][1] = fmaf(xa.x, wb.y, acc[0][1]);
      acc[0][2] = fmaf(xa.x, wb.z, acc[0][2]);
      acc[0][3] = fmaf(xa.x, wb.w, acc[0][3]);
      acc[1][0] = fmaf(xa.y, wb.x, acc[1][0]);
      acc[1][1] = fmaf(xa.y, wb.y, acc[1][1]);
      acc[1][2] = fmaf(xa.y, wb.z, acc[1][2]);
      acc[1][3] = fmaf(xa.y, wb.w, acc[1][3]);
      acc[2][0] = fmaf(xa.z, wb.x, acc[2][0]);
      acc[2][1] = fmaf(xa.z, wb.y, acc[2][1]);
      acc[2][2] = fmaf(xa.z, wb.z, acc[2][2]);
      acc[2][3] = fmaf(xa.z, wb.w, acc[2][3]);
      acc[3][0] = fmaf(xa.w, wb.x, acc[3][0]);
      acc[3][1] = fmaf(xa.w, wb.y, acc[3][1]);
      acc[3][2] = fmaf(xa.w, wb.z, acc[3][2]);
      acc[3][3] = fmaf(xa.w, wb.w, acc[3][3]);
    }
    __syncthreads();
  }
#pragma unroll
  for (int u = 0; u < 4; ++u) {
    float4 o;
    o.x = acc[u][0]; o.y = acc[u][1]; o.z = acc[u][2]; o.w = acc[u][3];
    *(float4*)(psum + (size_t)ks * 131072u + (size_t)(b0 + u) * 1024u +
               (ot * 32 + ol)) = o;
  }
}

// ---------------------------------------------------------------------------
// K4: out[b][o] = relu(sum_ks psum + bc[o])
// ---------------------------------------------------------------------------
__global__ __launch_bounds__(256) void k_final(
    const float* __restrict__ psum, const float* __restrict__ bc,
    float* __restrict__ out) {
  const int gid = blockIdx.x * 256 + threadIdx.x;  // 0..131071
  const int o = gid & 1023;
  float s = bc[o];
#pragma unroll
  for (int i = 0; i < 8; ++i) s += psum[(size_t)i * 131072u + gid];
  out[gid] = fmaxf(s, 0.f);
}

extern "C" void kernel_launch(void* const* d_in, const int* in_sizes, int n_in,
                              void* d_out, int out_size, void* d_ws,
                              size_t ws_size, hipStream_t stream) {
  const float* inp = (const float*)d_in[0];
  const float* hid = (const float*)d_in[1];
  const float* V   = (const float*)d_in[2];
  const float* W1  = (const float*)d_in[3];
  const float* b1  = (const float*)d_in[4];
  const float* W2  = (const float*)d_in[5];
  const float* b2  = (const float*)d_in[6];
  const float* Wc  = (const float*)d_in[7];
  const float* bc  = (const float*)d_in[8];
  float* out = (float*)d_out;
  float* ws = (float*)d_ws;

  float* tpart = ws + OFF_TPART;   // also psum for k_gemm2/k_final
  float* x0a   = ws + OFF_X0;
  float* y0a   = ws + OFF_Y0;
  float* wxn   = ws + OFF_WXN;
  float* wyn   = ws + OFF_WYN;
  float* attn  = ws + OFF_ATTN;

  k_gemm1<<<dim3(64, 8), 256, 0, stream>>>(hid, W1, tpart);
  k_align<<<128, 256, 0, stream>>>(tpart, b1, W2, b2, x0a, y0a, wxn, wyn);
  k_attn<<<dim3(128, 4), 512, 0, stream>>>(V, x0a, y0a, wxn, wyn, attn);
  k_gemm2<<<dim3(32, 8), 256, 0, stream>>>(inp, attn, Wc, tpart);
  k_final<<<512, 256, 0, stream>>>(tpart, bc, out);
}

// Round 3
// 737.047 us; speedup vs baseline: 1.1254x; 1.0081x over previous
//
#include <hip/hip_runtime.h>
#include <math.h>

// Problem constants
#define NB 128
#define HD 1024
#define FHH 24
#define FWW 48
#define MAXCELL 640   // >= ceil(pi*12^2) + pad slack

typedef float f4 __attribute__((ext_vector_type(4)));

// ws layout (float offsets). tpart region (8 MB) is reused as psum for the
// final GEMM (8*128*1024 floats fit inside 8*128*2048) since tpart is dead
// after k_align.
#define OFF_TPART 0u          // 8*128*2048 = 2097152
#define OFF_NC    2097152u    // 128 ints (padded cell count per b)
#define OFF_COFF  2097280u    // 128*640 uint element-offsets = 81920
#define OFF_CWTS  2179200u    // 128*640 float weights       = 81920
#define OFF_ATTN  2261120u    // 128*1024 floats

// ---------------------------------------------------------------------------
// K1a: tpart[ks][b][j] = sum_{k in ks-chunk(128)} hid[b,k] * W1[j,k]
// grid (64 j-tiles of 32, 8 k-chunks of 128), 256 threads.
// LDS transposed to [kk][b] / [kk][j] so fragment reads are ds_read_b128.
// ---------------------------------------------------------------------------
__global__ __launch_bounds__(256) void k_gemm1(
    const float* __restrict__ hid, const float* __restrict__ W1,
    float* __restrict__ tpart) {
  __shared__ float xs[32][132];   // [kk][b], pad 132
  __shared__ float wsh[32][36];   // [kk][j_local], pad 36
  const int tid = threadIdx.x;
  const int jt = blockIdx.x;
  const int ks = blockIdx.y;
  const int ty = tid >> 3, tx = tid & 7;
  const int b0 = ty * 4, jl = tx * 4;
  float acc[4][4] = {{0.f, 0.f, 0.f, 0.f}};
  for (int kt = 0; kt < 4; ++kt) {
    const int k0 = ks * 128 + kt * 32;
#pragma unroll
    for (int i = 0; i < 4; ++i) {
      int idx = tid + 256 * i;            // 0..1023 = 128 b x 8 q
      int bb = idx >> 3, q = idx & 7;
      float4 g = *(const float4*)(hid + bb * 1024 + k0 + q * 4);
      xs[q * 4 + 0][bb] = g.x;
      xs[q * 4 + 1][bb] = g.y;
      xs[q * 4 + 2][bb] = g.z;
      xs[q * 4 + 3][bb] = g.w;
    }
    {
      int o = tid >> 3, q = tid & 7;      // 32 rows x 8 quads
      float4 g = *(const float4*)(W1 + (size_t)(jt * 32 + o) * 1024 + k0 + q * 4);
      wsh[q * 4 + 0][o] = g.x;
      wsh[q * 4 + 1][o] = g.y;
      wsh[q * 4 + 2][o] = g.z;
      wsh[q * 4 + 3][o] = g.w;
    }
    __syncthreads();
#pragma unroll
    for (int kk = 0; kk < 32; ++kk) {
      float4 xa = *(const float4*)&xs[kk][b0];
      float4 wb = *(const float4*)&wsh[kk][jl];
      acc[0][0] = fmaf(xa.x, wb.x, acc[0][0]);
      acc[0][1] = fmaf(xa.x, wb.y, acc[0][1]);
      acc[0][2] = fmaf(xa.x, wb.z, acc[0][2]);
      acc[0][3] = fmaf(xa.x, wb.w, acc[0][3]);
      acc[1][0] = fmaf(xa.y, wb.x, acc[1][0]);
      acc[1][1] = fmaf(xa.y, wb.y, acc[1][1]);
      acc[1][2] = fmaf(xa.y, wb.z, acc[1][2]);
      acc[1][3] = fmaf(xa.y, wb.w, acc[1][3]);
      acc[2][0] = fmaf(xa.z, wb.x, acc[2][0]);
      acc[2][1] = fmaf(xa.z, wb.y, acc[2][1]);
      acc[2][2] = fmaf(xa.z, wb.z, acc[2][2]);
      acc[2][3] = fmaf(xa.z, wb.w, acc[2][3]);
      acc[3][0] = fmaf(xa.w, wb.x, acc[3][0]);
      acc[3][1] = fmaf(xa.w, wb.y, acc[3][1]);
      acc[3][2] = fmaf(xa.w, wb.z, acc[3][2]);
      acc[3][3] = fmaf(xa.w, wb.w, acc[3][3]);
    }
    __syncthreads();
  }
#pragma unroll
  for (int u = 0; u < 4; ++u) {
    float4 o;
    o.x = acc[u][0]; o.y = acc[u][1]; o.z = acc[u][2]; o.w = acc[u][3];
    *(float4*)(tpart + (size_t)ks * 262144u + (size_t)(b0 + u) * 2048u +
               (jt * 32 + jl)) = o;
  }
}

// ---------------------------------------------------------------------------
// K1b: per-b: t = tanh(sum_ks tpart + b1); algn = sigmoid(t@W2.T + b2);
// x0 = algn0*48, y0 = algn1*24. Then build the flattened truncated-window
// cell list: element offsets ((r*48+c)*128+b)*1024 and fused normalized
// weights wy[r]*wx[c], padded to a multiple of 64 with (0, 0.0f).
// Normalization over the FULL grid (exact). grid 128, 256 threads.
// ---------------------------------------------------------------------------
__global__ __launch_bounds__(256) void k_align(
    const float* __restrict__ tpart, const float* __restrict__ b1,
    const float* __restrict__ W2, const float* __restrict__ b2,
    int* __restrict__ ncnt, unsigned* __restrict__ goffs,
    float* __restrict__ gwts) {
  const int b = blockIdx.x;
  const int tid = threadIdx.x;
  float a0 = 0.f, a1 = 0.f;
#pragma unroll
  for (int i = 0; i < 8; ++i) {
    int j = tid + 256 * i;
    float s = b1[j];
#pragma unroll
    for (int ks = 0; ks < 8; ++ks)
      s += tpart[(size_t)ks * 262144u + (size_t)b * 2048u + j];
    float tv = tanhf(s);
    a0 += tv * W2[j];
    a1 += tv * W2[2048 + j];
  }
  __shared__ float r0[256], r1[256];
  r0[tid] = a0; r1[tid] = a1;
  __syncthreads();
  for (int s = 128; s > 0; s >>= 1) {
    if (tid < s) { r0[tid] += r0[tid + s]; r1[tid] += r1[tid + s]; }
    __syncthreads();
  }
  __shared__ float xy[2];
  __shared__ float wxl[48], wyl[24];
  __shared__ float invZ[2];
  if (tid == 0) {
    float p0 = 1.f / (1.f + expf(-(r0[0] + b2[0])));
    float p1 = 1.f / (1.f + expf(-(r1[0] + b2[1])));
    xy[0] = p0 * 48.f;
    xy[1] = p1 * 24.f;
  }
  __syncthreads();
  const float x0 = xy[0], y0 = xy[1];
  if (tid < 48) {
    float d = (float)tid - x0;
    wxl[tid] = expf(-d * d * (1.f / 32.f));
  } else if (tid >= 64 && tid < 88) {
    int r = tid - 64;
    float d = (float)r - y0;
    wyl[r] = expf(-d * d * (1.f / 32.f));
  }
  __syncthreads();
  if (tid == 0) {
    float zx = 0.f, zy = 0.f;
    for (int c = 0; c < 48; ++c) zx += wxl[c];
    for (int r = 0; r < 24; ++r) zy += wyl[r];
    invZ[0] = 1.f / zx;
    invZ[1] = 1.f / zy;
  }
  __syncthreads();
  // --- build cell list ---
  __shared__ int c0s[24], cnts[24], rowst[24];
  __shared__ int tot[2];   // [0]=total, [1]=padded
  const int rlo = max(0, (int)ceilf(y0 - 12.f));
  const int rhi = min(23, (int)floorf(y0 + 12.f));
  if (tid < 24) {
    int cnt = 0, c0 = 0;
    if (tid >= rlo && tid <= rhi) {
      float dy = (float)tid - y0;
      float rad = sqrtf(fmaxf(144.f - dy * dy, 0.f));
      c0 = max(0, (int)ceilf(x0 - rad));
      int c1 = min(47, (int)floorf(x0 + rad));
      cnt = (c1 >= c0) ? (c1 - c0 + 1) : 0;
    }
    c0s[tid] = c0;
    cnts[tid] = cnt;
  }
  __syncthreads();
  if (tid == 0) {
    int run = 0;
    for (int r = 0; r < 24; ++r) { rowst[r] = run; run += cnts[r]; }
    tot[0] = run;
    tot[1] = (run + 63) & ~63;
  }
  __syncthreads();
  const float izx = invZ[0], izy = invZ[1];
#pragma unroll
  for (int r = 0; r < 24; ++r) {
    if (tid < cnts[r]) {
      int c = c0s[r] + tid;
      int e = rowst[r] + tid;
      goffs[b * MAXCELL + e] = (unsigned)((r * 48 + c) * 128 + b) * 1024u;
      gwts[b * MAXCELL + e] = (wyl[r] * izy) * (wxl[c] * izx);
    }
  }
  for (int e = tot[0] + tid; e < tot[1]; e += 256) {
    goffs[b * MAXCELL + e] = 0u;
    gwts[b * MAXCELL + e] = 0.f;
  }
  if (tid == 0) ncnt[b] = tot[1];
}

// ---------------------------------------------------------------------------
// K2: attn[b][h] = sum over the precomputed cell list of w[i] * V[off[i]+h].
// grid (128 b, 4 h-quarters), 512 threads = 8 waves. Wave w takes 8-entry
// chunks at stride 64 -> uniform control flow, 8 independent 16B nt-loads in
// flight per lane. Cross-wave LDS reduce writes attn directly.
// ---------------------------------------------------------------------------
__global__ __launch_bounds__(512) void k_attn(
    const float* __restrict__ V, const int* __restrict__ ncnt,
    const unsigned* __restrict__ goffs, const float* __restrict__ gwts,
    float* __restrict__ attn) {
  const int b = blockIdx.x;
  const int qtr = blockIdx.y;
  const int tid = threadIdx.x;
  const int w = tid >> 6;
  const int lane = tid & 63;
  __shared__ unsigned offs_l[MAXCELL];
  __shared__ float wts_l[MAXCELL];
  const int npad = ncnt[b];
  for (int i = tid; i < npad; i += 512) {
    offs_l[i] = goffs[b * MAXCELL + i];
    wts_l[i] = gwts[b * MAXCELL + i];
  }
  __syncthreads();
  const int h0 = qtr * 256 + lane * 4;
  f4 acc = {0.f, 0.f, 0.f, 0.f};
  for (int t = w * 8; t < npad; t += 64) {
#pragma unroll
    for (int u = 0; u < 8; ++u) {
      unsigned off = offs_l[t + u];
      float wgt = wts_l[t + u];
      f4 v = __builtin_nontemporal_load((const f4*)(V + off + h0));
      acc.x = fmaf(wgt, v.x, acc.x);
      acc.y = fmaf(wgt, v.y, acc.y);
      acc.z = fmaf(wgt, v.z, acc.z);
      acc.w = fmaf(wgt, v.w, acc.w);
    }
  }
  __shared__ float red[8][260];
  *(f4*)&red[w][lane * 4] = acc;
  __syncthreads();
  if (tid < 256) {
    float s = 0.f;
#pragma unroll
    for (int ww = 0; ww < 8; ++ww) s += red[ww][tid];
    attn[(size_t)b * 1024u + qtr * 256 + tid] = s;
  }
}

// ---------------------------------------------------------------------------
// K3: psum[ks][b][o] = sum_{k in ks-chunk(256)} x[b,k] * Wc[o,k],
// x = concat(inp, attn). grid (32 o-tiles, 8 k-chunks), 256 threads.
// ---------------------------------------------------------------------------
__global__ __launch_bounds__(256) void k_gemm2(
    const float* __restrict__ inp, const float* __restrict__ attn,
    const float* __restrict__ Wc, float* __restrict__ psum) {
  __shared__ float xs[32][132];
  __shared__ float wsh[32][36];
  const int tid = threadIdx.x;
  const int ot = blockIdx.x;
  const int ks = blockIdx.y;
  const int ty = tid >> 3, tx = tid & 7;
  const int b0 = ty * 4, ol = tx * 4;
  const float* xsrc = (ks < 4) ? inp : attn;
  const int kbase = (ks < 4) ? ks * 256 : (ks - 4) * 256;
  float acc[4][4] = {{0.f, 0.f, 0.f, 0.f}};
  for (int kt = 0; kt < 8; ++kt) {
    const int k0g = ks * 256 + kt * 32;      // index into Wc's K dim
    const int k0x = kbase + kt * 32;         // index into xsrc
#pragma unroll
    for (int i = 0; i < 4; ++i) {
      int idx = tid + 256 * i;
      int bb = idx >> 3, q = idx & 7;
      float4 g = *(const float4*)(xsrc + bb * 1024 + k0x + q * 4);
      xs[q * 4 + 0][bb] = g.x;
      xs[q * 4 + 1][bb] = g.y;
      xs[q * 4 + 2][bb] = g.z;
      xs[q * 4 + 3][bb] = g.w;
    }
    {
      int o = tid >> 3, q = tid & 7;
      float4 g = *(const float4*)(Wc + (size_t)(ot * 32 + o) * 2048u + k0g + q * 4);
      wsh[q * 4 + 0][o] = g.x;
      wsh[q * 4 + 1][o] = g.y;
      wsh[q * 4 + 2][o] = g.z;
      wsh[q * 4 + 3][o] = g.w;
    }
    __syncthreads();
#pragma unroll
    for (int kk = 0; kk < 32; ++kk) {
      float4 xa = *(const float4*)&xs[kk][b0];
      float4 wb = *(const float4*)&wsh[kk][ol];
      acc[0][0] = fmaf(xa.x, wb.x, acc[0][0]);
      acc[0][1] = fmaf(xa.x, wb.y, acc[0][1]);
      acc[0][2] = fmaf(xa.x, wb.z, acc[0][2]);
      acc[0][3] = fmaf(xa.x, wb.w, acc[0][3]);
      acc[1][0] = fmaf(xa.y, wb.x, acc[1][0]);
      acc[1][1] = fmaf(xa.y, wb.y, acc[1][1]);
      acc[1][2] = fmaf(xa.y, wb.z, acc[1][2]);
      acc[1][3] = fmaf(xa.y, wb.w, acc[1][3]);
      acc[2][0] = fmaf(xa.z, wb.x, acc[2][0]);
      acc[2][1] = fmaf(xa.z, wb.y, acc[2][1]);
      acc[2][2] = fmaf(xa.z, wb.z, acc[2][2]);
      acc[2][3] = fmaf(xa.z, wb.w, acc[2][3]);
      acc[3][0] = fmaf(xa.w, wb.x, acc[3][0]);
      acc[3][1] = fmaf(xa.w, wb.y, acc[3][1]);
      acc[3][2] = fmaf(xa.w, wb.z, acc[3][2]);
      acc[3][3] = fmaf(xa.w, wb.w, acc[3][3]);
    }
    __syncthreads();
  }
#pragma unroll
  for (int u = 0; u < 4; ++u) {
    float4 o;
    o.x = acc[u][0]; o.y = acc[u][1]; o.z = acc[u][2]; o.w = acc[u][3];
    *(float4*)(psum + (size_t)ks * 131072u + (size_t)(b0 + u) * 1024u +
               (ot * 32 + ol)) = o;
  }
}

// ---------------------------------------------------------------------------
// K4: out[b][o] = relu(sum_ks psum + bc[o])
// ---------------------------------------------------------------------------
__global__ __launch_bounds__(256) void k_final(
    const float* __restrict__ psum, const float* __restrict__ bc,
    float* __restrict__ out) {
  const int gid = blockIdx.x * 256 + threadIdx.x;  // 0..131071
  const int o = gid & 1023;
  float s = bc[o];
#pragma unroll
  for (int i = 0; i < 8; ++i) s += psum[(size_t)i * 131072u + gid];
  out[gid] = fmaxf(s, 0.f);
}

extern "C" void kernel_launch(void* const* d_in, const int* in_sizes, int n_in,
                              void* d_out, int out_size, void* d_ws,
                              size_t ws_size, hipStream_t stream) {
  const float* inp = (const float*)d_in[0];
  const float* hid = (const float*)d_in[1];
  const float* V   = (const float*)d_in[2];
  const float* W1  = (const float*)d_in[3];
  const float* b1  = (const float*)d_in[4];
  const float* W2  = (const float*)d_in[5];
  const float* b2  = (const float*)d_in[6];
  const float* Wc  = (const float*)d_in[7];
  const float* bc  = (const float*)d_in[8];
  float* out = (float*)d_out;
  float* ws = (float*)d_ws;

  float* tpart    = ws + OFF_TPART;   // also psum for k_gemm2/k_final
  int* ncnt       = (int*)(ws + OFF_NC);
  unsigned* goffs = (unsigned*)(ws + OFF_COFF);
  float* gwts     = ws + OFF_CWTS;
  float* attn     = ws + OFF_ATTN;

  k_gemm1<<<dim3(64, 8), 256, 0, stream>>>(hid, W1, tpart);
  k_align<<<128, 256, 0, stream>>>(tpart, b1, W2, b2, ncnt, goffs, gwts);
  k_attn<<<dim3(128, 4), 512, 0, stream>>>(V, ncnt, goffs, gwts, attn);
  k_gemm2<<<dim3(32, 8), 256, 0, stream>>>(inp, attn, Wc, tpart);
  k_final<<<512, 256, 0, stream>>>(tpart, bc, out);
}